// Round 3
// baseline (668.552 us; speedup 1.0000x reference)
//
#include <hip/hip_runtime.h>
#include <cstdint>

#define NPTS   16384
#define BATCH  4
#define BNP    65536
#define CIN    64
#define KNB    16
#define COUT   128
#define NGRP   (BNP / KNB)     // 4096 groups of 16 points
#define BN_EPS 1e-5f

typedef __attribute__((ext_vector_type(8))) short     short8;
typedef __attribute__((ext_vector_type(4))) float     f32x4;
typedef __attribute__((ext_vector_type(2))) unsigned  u32x2;
typedef __attribute__((ext_vector_type(4))) int       i32x4;

// wait until <= n vector-memory ops outstanding (lgkm=15, exp=7 = no wait)
#define WAITVM(n) __builtin_amdgcn_s_waitcnt(0x0F70 | (n))

__device__ __forceinline__ unsigned short f2bf(float f) {   // RNE
    unsigned u = __float_as_uint(f);
    u += 0x7FFFu + ((u >> 16) & 1u);
    return (unsigned short)(u >> 16);
}
__device__ __forceinline__ float bf2f(unsigned short h) {
    return __uint_as_float(((unsigned)h) << 16);
}

// ---------------- K0: feature [B][C][N] -> flat bf16 [B*N][64]; zero part ----
__global__ __launch_bounds__(256) void k_prep(const float* __restrict__ feat,
                                              unsigned short* __restrict__ fb,
                                              float* __restrict__ part)
{
    __shared__ float t[CIN][CIN + 1];
    int blk = blockIdx.x;
    if (blk == 0 && threadIdx.x < 2 * COUT) part[threadIdx.x] = 0.f;
    int b   = blk >> 8;
    int n0  = (blk & 255) << 6;
    int sub = threadIdx.x >> 6, lane = threadIdx.x & 63;
    const float* fp = feat + (size_t)b * CIN * NPTS;
    #pragma unroll
    for (int r = 0; r < CIN; r += 4) {
        int c = r + sub;
        t[c][lane] = fp[(size_t)c * NPTS + n0 + lane];     // coalesced along n
    }
    __syncthreads();
    unsigned short* ob = fb + (size_t)(b * NPTS + n0) * CIN;
    #pragma unroll
    for (int r = 0; r < CIN; r += 4) {
        int x = r + sub;
        ob[(size_t)x * CIN + lane] = f2bf(t[lane][x]);
    }
}

// ---------------- K1: MFMA gather + attention + pooled linear ----------------
// Per wave: one group of 16 points x 16 neighbors.
// k-loop: phase1 score^T = Wm x spir^T (8 MFMA) ; softmax over d (16 exp + 2
// shfl) ; pooled[16] += attn*spir in fp32 regs (no per-k phase2).
// After k-loop: pooled -> plds -> one phase2 (16 MFMA, Wc from LDS).
// spir DMA layout is XOR-swizzled: LDS slot q of row pt holds global quarter
// (q + (pt>>1)) & 3 -> all spir reads spread over 8 bank-groups (<=2-way).
__global__ __launch_bounds__(256, 3) void k_main(
    const unsigned short* __restrict__ fb,   // [BNP][64] bf16
    const int* __restrict__ nidx,            // [BNP][16]
    const float* __restrict__ Wm,            // [64][64]
    const float* __restrict__ Wc,            // [128][64]
    float* __restrict__ out,                 // [4][128][16384] pre-BN
    float* __restrict__ part)                // [256] atomic BN partials
{
    __shared__ __align__(16) unsigned short spir[4][2][1024]; // 16 KB dbuf
    __shared__ __align__(16) unsigned short plds[4][16 * 72]; //  9 KB
    __shared__ __align__(16) unsigned short wcl[COUT * 72];   // 18 KB

    const int tid  = threadIdx.x;
    const int wv   = tid >> 6;
    const int lane = tid & 63;
    const int ptc  = lane & 15;
    const int qg   = lane >> 4;
    const int pt4  = lane >> 2;
    const int q4   = lane & 3;
    const int swq  = ptc >> 1;              // read-side swizzle rotation
    const int Qg   = (q4 + (pt4 >> 1)) & 3; // quarter this lane DMAs

    // stage Wc -> LDS bf16, stride 72 (conflict-free A-frag reads)
    for (int e = tid; e < COUT * CIN; e += 256)
        wcl[(e >> 6) * 72 + (e & 63)] = f2bf(Wc[e]);

    // Wm A-fragments in registers: A[m=ptc][k=qg*8+j (+32*ks)]
    short8 wmF[4][2];
    #pragma unroll
    for (int mt = 0; mt < 4; ++mt)
        #pragma unroll
        for (int ks = 0; ks < 2; ++ks) {
            const float* p = Wm + (size_t)(mt * 16 + ptc) * CIN + qg * 8 + ks * 32;
            short8 v;
            #pragma unroll
            for (int j = 0; j < 8; ++j) v[j] = (short)f2bf(p[j]);
            wmF[mt][ks] = v;
        }
    __syncthreads();

    for (int g = blockIdx.x * 4 + wv; g < NGRP; g += (gridDim.x << 2)) {
        i32x4 iv = *(const i32x4*)(nidx + (size_t)g * 256 + lane * 4);

        auto issue = [&](int k, int bf) {
            int id = __shfl(iv[k & 3], (lane & ~3) | (k >> 2));
            const unsigned short* gp = fb + (size_t)id * CIN + Qg * 8;
            __builtin_amdgcn_global_load_lds(
                (const __attribute__((address_space(1))) unsigned int*)(const void*)gp,
                (__attribute__((address_space(3))) unsigned int*)(void*)&spir[wv][bf][0],
                16, 0, 0);
            __builtin_amdgcn_global_load_lds(
                (const __attribute__((address_space(1))) unsigned int*)(const void*)(gp + 32),
                (__attribute__((address_space(3))) unsigned int*)(void*)&spir[wv][bf][512],
                16, 0, 0);
        };

        issue(0, 0);
        issue(1, 1);

        float pooled[16];
        #pragma unroll
        for (int i = 0; i < 16; ++i) pooled[i] = 0.f;

        #pragma unroll
        for (int k = 0; k < KNB; ++k) {
            const int bf = k & 1;
            if (k < KNB - 1) WAITVM(2); else WAITVM(0);    // buf k landed
            __asm__ volatile("" ::: "memory");

            // ---- phase 1: score^T[d, pt] = Wm x spir^T ----
            const int so = (qg - swq) & 3;                 // swizzled slot
            short8 b1_0 = *(const short8*)&spir[wv][bf][      ptc * 32 + so * 8];
            short8 b1_1 = *(const short8*)&spir[wv][bf][512 + ptc * 32 + so * 8];
            f32x4 zero4 = (f32x4){0.f, 0.f, 0.f, 0.f};
            f32x4 a1[4];
            #pragma unroll
            for (int mt = 0; mt < 4; ++mt) {
                f32x4 t0 = __builtin_amdgcn_mfma_f32_16x16x32_bf16(wmF[mt][0], b1_0, zero4, 0, 0, 0);
                a1[mt]   = __builtin_amdgcn_mfma_f32_16x16x32_bf16(wmF[mt][1], b1_1, t0,    0, 0, 0);
            }

            // ---- softmax over d: 16 in-lane exps + xor16/xor32 ----
            float e[16], s = 0.f;
            #pragma unroll
            for (int mt = 0; mt < 4; ++mt)
                #pragma unroll
                for (int r = 0; r < 4; ++r) {
                    float x = __expf(a1[mt][r]);
                    e[mt * 4 + r] = x;
                    s += x;
                }
            s += __shfl_xor(s, 16);
            s += __shfl_xor(s, 32);
            float inv = __builtin_amdgcn_rcpf(s);

            // ---- pooled[d] += attn * spir (fp32 registers, per-lane d's) ----
            #pragma unroll
            for (int mt = 0; mt < 4; ++mt) {
                const int h  = mt >> 1;
                const int Qh = (mt & 1) * 2 + (qg >> 1);
                const int sl = (Qh - swq) & 3;
                u32x2 sv = *(const u32x2*)&spir[wv][bf]
                    [h * 512 + ptc * 32 + sl * 8 + (qg & 1) * 4];
                unsigned lo = sv[0], hi = sv[1];
                pooled[mt*4+0] = fmaf(bf2f((unsigned short)lo)         , e[mt*4+0] * inv, pooled[mt*4+0]);
                pooled[mt*4+1] = fmaf(bf2f((unsigned short)(lo >> 16)) , e[mt*4+1] * inv, pooled[mt*4+1]);
                pooled[mt*4+2] = fmaf(bf2f((unsigned short)hi)         , e[mt*4+2] * inv, pooled[mt*4+2]);
                pooled[mt*4+3] = fmaf(bf2f((unsigned short)(hi >> 16)) , e[mt*4+3] * inv, pooled[mt*4+3]);
            }

            if (k < KNB - 2) issue(k + 2, bf);             // dbuf refill
        }

        // ---- stage pooled -> plds (bf16, B-layout), one phase 2 ----
        #pragma unroll
        for (int mt = 0; mt < 4; ++mt) {
            unsigned w0 = ((__float_as_uint(pooled[mt*4+0]) + 0x8000u) >> 16) |
                          ((__float_as_uint(pooled[mt*4+1]) + 0x8000u) & 0xFFFF0000u);
            unsigned w1 = ((__float_as_uint(pooled[mt*4+2]) + 0x8000u) >> 16) |
                          ((__float_as_uint(pooled[mt*4+3]) + 0x8000u) & 0xFFFF0000u);
            *(u32x2*)&plds[wv][ptc * 72 + mt * 16 + qg * 4] = (u32x2){w0, w1};
        }
        short8 b2_0 = *(const short8*)&plds[wv][ptc * 72 +      qg * 8];
        short8 b2_1 = *(const short8*)&plds[wv][ptc * 72 + 32 + qg * 8];

        f32x4 acc2[8];
        #pragma unroll
        for (int mt = 0; mt < 8; ++mt) {
            short8 wa0 = *(const short8*)&wcl[(mt * 16 + ptc) * 72 +      qg * 8];
            short8 wa1 = *(const short8*)&wcl[(mt * 16 + ptc) * 72 + 32 + qg * 8];
            f32x4 t0 = __builtin_amdgcn_mfma_f32_16x16x32_bf16(wa0, b2_0, (f32x4){0.f,0.f,0.f,0.f}, 0, 0, 0);
            acc2[mt] = __builtin_amdgcn_mfma_f32_16x16x32_bf16(wa1, b2_1, t0, 0, 0, 0);
        }

        // ---- epilogue: store pre-BN out + fused BN partials ----
        int p0 = g << 4;
        int b  = p0 >> 14;
        int nn = (p0 & (NPTS - 1)) + ptc;
        float* ob = out + (((size_t)(b * COUT)) << 14) + nn;
        #pragma unroll
        for (int mt = 0; mt < 8; ++mt)
            #pragma unroll
            for (int r = 0; r < 4; ++r) {
                float v = acc2[mt][r];
                ob[((size_t)(mt * 16 + qg * 4 + r)) << 14] = v;
                float s = v, q = v * v;
                #pragma unroll
                for (int off = 1; off <= 8; off <<= 1) {
                    s += __shfl_xor(s, off);
                    q += __shfl_xor(q, off);
                }
                if (ptc == 0) {
                    int o = mt * 16 + qg * 4 + r;
                    atomicAdd(&part[o], s);
                    atomicAdd(&part[COUT + o], q);
                }
            }
    }
}

// ---------------- K2: per-block stats finalize + apply BN in place ----------
__global__ __launch_bounds__(256) void k_apply(float* __restrict__ out,
                                               const float* __restrict__ part,
                                               const float* __restrict__ gamma,
                                               const float* __restrict__ beta)
{
    __shared__ float sc[COUT], sh[COUT];
    int t = threadIdx.x;
    if (t < COUT) {
        float mean = part[t]        * (1.0f / BNP);
        float ex2  = part[COUT + t] * (1.0f / BNP);
        float var  = ex2 - mean * mean;
        float a = gamma[t] * rsqrtf(var + BN_EPS);
        sc[t] = a; sh[t] = beta[t] - mean * a;
    }
    __syncthreads();
    const int total4 = BATCH * COUT * NPTS / 4;
    for (int i = blockIdx.x * 256 + t; i < total4; i += gridDim.x * 256) {
        int ch = (i >> 12) & 127;
        float4 v = ((float4*)out)[i];
        float a = sc[ch], b2 = sh[ch];
        v.x = fmaf(v.x, a, b2); v.y = fmaf(v.y, a, b2);
        v.z = fmaf(v.z, a, b2); v.w = fmaf(v.w, a, b2);
        ((float4*)out)[i] = v;
    }
}

extern "C" void kernel_launch(void* const* d_in, const int* in_sizes, int n_in,
                              void* d_out, int out_size, void* d_ws, size_t ws_size,
                              hipStream_t stream)
{
    const float* feat  = (const float*)d_in[0];
    const int*   nidx  = (const int*)  d_in[1];
    // d_in[2] = permatrix (unused); d_in[5] = b_conv (exactly absorbed by BN)
    const float* Wm    = (const float*)d_in[3];
    const float* Wc    = (const float*)d_in[4];
    const float* gamma = (const float*)d_in[6];
    const float* beta  = (const float*)d_in[7];
    float* out = (float*)d_out;

    unsigned short* fb = (unsigned short*)d_ws;                      // 8.4 MB
    float* part = (float*)((char*)d_ws + (size_t)BNP * CIN * 2);     // 256 floats

    k_prep <<<1024, 256, 0, stream>>>(feat, fb, part);
    k_main <<<1024, 256, 0, stream>>>(fb, nidx, Wm, Wc, out, part);
    k_apply<<<2048, 256, 0, stream>>>(out, part, gamma, beta);
}

// Round 4
// 232.882 us; speedup vs baseline: 2.8708x; 2.8708x over previous
//
#include <hip/hip_runtime.h>
#include <cstdint>

#define NPTS   16384
#define BATCH  4
#define BNP    65536
#define CIN    64
#define KNB    16
#define COUT   128
#define NGRP   (BNP / KNB)     // 4096 groups of 16 points
#define K1_GRID 512            // k_main blocks; each wave does NGRP/(K1_GRID*4)=2 groups
#define BN_EPS 1e-5f

typedef __attribute__((ext_vector_type(8))) short     short8;
typedef __attribute__((ext_vector_type(4))) float     f32x4;
typedef __attribute__((ext_vector_type(2))) unsigned  u32x2;
typedef __attribute__((ext_vector_type(4))) int       i32x4;

// wait until <= n vector-memory ops outstanding (lgkm=15, exp=7 = no wait)
#define WAITVM(n) __builtin_amdgcn_s_waitcnt(0x0F70 | (n))

__device__ __forceinline__ unsigned short f2bf(float f) {   // RNE
    unsigned u = __float_as_uint(f);
    u += 0x7FFFu + ((u >> 16) & 1u);
    return (unsigned short)(u >> 16);
}
__device__ __forceinline__ float bf2f(unsigned short h) {
    return __uint_as_float(((unsigned)h) << 16);
}

// ---------------- K0: feature [B][C][N] -> flat bf16 [B*N][64] ----------------
__global__ __launch_bounds__(256) void k_prep(const float* __restrict__ feat,
                                              unsigned short* __restrict__ fb)
{
    __shared__ float t[CIN][CIN + 1];
    int blk = blockIdx.x;
    int b   = blk >> 8;
    int n0  = (blk & 255) << 6;
    int sub = threadIdx.x >> 6, lane = threadIdx.x & 63;
    const float* fp = feat + (size_t)b * CIN * NPTS;
    #pragma unroll
    for (int r = 0; r < CIN; r += 4) {
        int c = r + sub;
        t[c][lane] = fp[(size_t)c * NPTS + n0 + lane];     // coalesced along n
    }
    __syncthreads();
    unsigned short* ob = fb + (size_t)(b * NPTS + n0) * CIN;
    #pragma unroll
    for (int r = 0; r < CIN; r += 4) {
        int x = r + sub;
        ob[(size_t)x * CIN + lane] = f2bf(t[lane][x]);
    }
}

// ---------------- K1: MFMA gather + attention + pooled linear ----------------
// Per wave: groups of 16 points x 16 neighbors (2 groups/wave).
// k-loop: phase1 score^T = Wm x spir^T (8 MFMA) ; softmax over d (16 exp + 2
// shfl) ; pooled[16] += attn*spir in fp32 regs. After k-loop: pooled -> plds
// -> one phase2 (16 MFMA, Wc from LDS). BN partials: shuffle-reduce over ptc
// -> LDS atomicAdd (block-shared, contention-free) -> one coalesced store.
__global__ __launch_bounds__(256, 3) void k_main(
    const unsigned short* __restrict__ fb,   // [BNP][64] bf16
    const int* __restrict__ nidx,            // [BNP][16]
    const float* __restrict__ Wm,            // [64][64]
    const float* __restrict__ Wc,            // [128][64]
    float* __restrict__ out,                 // [4][128][16384] pre-BN
    float* __restrict__ part)                // [K1_GRID][256] block partials
{
    __shared__ __align__(16) unsigned short spir[4][2][1024]; // 16 KB dbuf
    __shared__ __align__(16) unsigned short plds[4][16 * 72]; //  9 KB
    __shared__ __align__(16) unsigned short wcl[COUT * 72];   // 18 KB
    __shared__ float bnp[2 * COUT];                           //  1 KB

    const int tid  = threadIdx.x;
    const int wv   = tid >> 6;
    const int lane = tid & 63;
    const int ptc  = lane & 15;
    const int qg   = lane >> 4;
    const int pt4  = lane >> 2;
    const int q4   = lane & 3;
    const int swq  = ptc >> 1;              // read-side swizzle rotation
    const int Qg   = (q4 + (pt4 >> 1)) & 3; // quarter this lane DMAs

    bnp[tid] = 0.f;

    // stage Wc -> LDS bf16, stride 72 (conflict-free A-frag reads)
    for (int e = tid; e < COUT * CIN; e += 256)
        wcl[(e >> 6) * 72 + (e & 63)] = f2bf(Wc[e]);

    // Wm A-fragments in registers: A[m=ptc][k=qg*8+j (+32*ks)]
    short8 wmF[4][2];
    #pragma unroll
    for (int mt = 0; mt < 4; ++mt)
        #pragma unroll
        for (int ks = 0; ks < 2; ++ks) {
            const float* p = Wm + (size_t)(mt * 16 + ptc) * CIN + qg * 8 + ks * 32;
            short8 v;
            #pragma unroll
            for (int j = 0; j < 8; ++j) v[j] = (short)f2bf(p[j]);
            wmF[mt][ks] = v;
        }
    __syncthreads();

    for (int g = blockIdx.x * 4 + wv; g < NGRP; g += K1_GRID * 4) {
        i32x4 iv = *(const i32x4*)(nidx + (size_t)g * 256 + lane * 4);

        auto issue = [&](int k, int bf) {
            int id = __shfl(iv[k & 3], (lane & ~3) | (k >> 2));
            const unsigned short* gp = fb + (size_t)id * CIN + Qg * 8;
            __builtin_amdgcn_global_load_lds(
                (const __attribute__((address_space(1))) unsigned int*)(const void*)gp,
                (__attribute__((address_space(3))) unsigned int*)(void*)&spir[wv][bf][0],
                16, 0, 0);
            __builtin_amdgcn_global_load_lds(
                (const __attribute__((address_space(1))) unsigned int*)(const void*)(gp + 32),
                (__attribute__((address_space(3))) unsigned int*)(void*)&spir[wv][bf][512],
                16, 0, 0);
        };

        issue(0, 0);
        issue(1, 1);

        float pooled[16];
        #pragma unroll
        for (int i = 0; i < 16; ++i) pooled[i] = 0.f;

        #pragma unroll
        for (int k = 0; k < KNB; ++k) {
            const int bf = k & 1;
            if (k < KNB - 1) WAITVM(2); else WAITVM(0);    // buf k landed
            __asm__ volatile("" ::: "memory");

            // ---- phase 1: score^T[d, pt] = Wm x spir^T ----
            const int so = (qg - swq) & 3;                 // swizzled slot
            short8 b1_0 = *(const short8*)&spir[wv][bf][      ptc * 32 + so * 8];
            short8 b1_1 = *(const short8*)&spir[wv][bf][512 + ptc * 32 + so * 8];
            f32x4 zero4 = (f32x4){0.f, 0.f, 0.f, 0.f};
            f32x4 a1[4];
            #pragma unroll
            for (int mt = 0; mt < 4; ++mt) {
                f32x4 t0 = __builtin_amdgcn_mfma_f32_16x16x32_bf16(wmF[mt][0], b1_0, zero4, 0, 0, 0);
                a1[mt]   = __builtin_amdgcn_mfma_f32_16x16x32_bf16(wmF[mt][1], b1_1, t0,    0, 0, 0);
            }

            // ---- softmax over d: 16 in-lane exps + xor16/xor32 ----
            float e[16], s = 0.f;
            #pragma unroll
            for (int mt = 0; mt < 4; ++mt)
                #pragma unroll
                for (int r = 0; r < 4; ++r) {
                    float x = __expf(a1[mt][r]);
                    e[mt * 4 + r] = x;
                    s += x;
                }
            s += __shfl_xor(s, 16);
            s += __shfl_xor(s, 32);
            float inv = __builtin_amdgcn_rcpf(s);

            // ---- pooled[d] += attn * spir (fp32 registers, per-lane d's) ----
            #pragma unroll
            for (int mt = 0; mt < 4; ++mt) {
                const int h  = mt >> 1;
                const int Qh = (mt & 1) * 2 + (qg >> 1);
                const int sl = (Qh - swq) & 3;
                u32x2 sv = *(const u32x2*)&spir[wv][bf]
                    [h * 512 + ptc * 32 + sl * 8 + (qg & 1) * 4];
                unsigned lo = sv[0], hi = sv[1];
                pooled[mt*4+0] = fmaf(bf2f((unsigned short)lo)         , e[mt*4+0] * inv, pooled[mt*4+0]);
                pooled[mt*4+1] = fmaf(bf2f((unsigned short)(lo >> 16)) , e[mt*4+1] * inv, pooled[mt*4+1]);
                pooled[mt*4+2] = fmaf(bf2f((unsigned short)hi)         , e[mt*4+2] * inv, pooled[mt*4+2]);
                pooled[mt*4+3] = fmaf(bf2f((unsigned short)(hi >> 16)) , e[mt*4+3] * inv, pooled[mt*4+3]);
            }

            if (k < KNB - 2) issue(k + 2, bf);             // dbuf refill
        }

        // ---- stage pooled -> plds (bf16, B-layout), one phase 2 ----
        #pragma unroll
        for (int mt = 0; mt < 4; ++mt) {
            unsigned w0 = ((__float_as_uint(pooled[mt*4+0]) + 0x8000u) >> 16) |
                          ((__float_as_uint(pooled[mt*4+1]) + 0x8000u) & 0xFFFF0000u);
            unsigned w1 = ((__float_as_uint(pooled[mt*4+2]) + 0x8000u) >> 16) |
                          ((__float_as_uint(pooled[mt*4+3]) + 0x8000u) & 0xFFFF0000u);
            *(u32x2*)&plds[wv][ptc * 72 + mt * 16 + qg * 4] = (u32x2){w0, w1};
        }
        short8 b2_0 = *(const short8*)&plds[wv][ptc * 72 +      qg * 8];
        short8 b2_1 = *(const short8*)&plds[wv][ptc * 72 + 32 + qg * 8];

        f32x4 acc2[8];
        #pragma unroll
        for (int mt = 0; mt < 8; ++mt) {
            short8 wa0 = *(const short8*)&wcl[(mt * 16 + ptc) * 72 +      qg * 8];
            short8 wa1 = *(const short8*)&wcl[(mt * 16 + ptc) * 72 + 32 + qg * 8];
            f32x4 t0 = __builtin_amdgcn_mfma_f32_16x16x32_bf16(wa0, b2_0, (f32x4){0.f,0.f,0.f,0.f}, 0, 0, 0);
            acc2[mt] = __builtin_amdgcn_mfma_f32_16x16x32_bf16(wa1, b2_1, t0, 0, 0, 0);
        }

        // ---- epilogue: store pre-BN out ----
        int p0 = g << 4;
        int b  = p0 >> 14;
        int nn = (p0 & (NPTS - 1)) + ptc;
        float* ob = out + (((size_t)(b * COUT)) << 14) + nn;
        #pragma unroll
        for (int mt = 0; mt < 8; ++mt)
            #pragma unroll
            for (int r = 0; r < 4; ++r)
                ob[((size_t)(mt * 16 + qg * 4 + r)) << 14] = acc2[mt][r];

        // ---- BN partials: shuffle-reduce over ptc, LDS atomic accumulate ----
        #pragma unroll
        for (int mt = 0; mt < 8; ++mt)
            #pragma unroll
            for (int r = 0; r < 4; ++r) {
                float s = acc2[mt][r], q = s * s;
                #pragma unroll
                for (int off = 1; off <= 8; off <<= 1) {
                    s += __shfl_xor(s, off);
                    q += __shfl_xor(q, off);
                }
                if (ptc == 0) {
                    int o = mt * 16 + qg * 4 + r;
                    atomicAdd(&bnp[o], s);          // ds_add_f32, block-local
                    atomicAdd(&bnp[COUT + o], q);
                }
            }
    }

    __syncthreads();
    part[(size_t)blockIdx.x * 256 + tid] = bnp[tid];   // coalesced, deterministic
}

// ---------------- K2: reduce block partials -> per-channel scale/shift ------
__global__ __launch_bounds__(256) void k_stats(const float* __restrict__ part,
                                               const float* __restrict__ gamma,
                                               const float* __restrict__ beta,
                                               float* __restrict__ scalesh)
{
    int c = blockIdx.x;        // channel 0..127
    int t = threadIdx.x;
    float s = 0.f, q = 0.f;
    for (int r = t; r < K1_GRID; r += 256) {
        s += part[(size_t)r * 256 + c];
        q += part[(size_t)r * 256 + COUT + c];
    }
    #pragma unroll
    for (int off = 32; off >= 1; off >>= 1) {
        s += __shfl_xor(s, off);
        q += __shfl_xor(q, off);
    }
    __shared__ float ls[4], lq[4];
    if ((t & 63) == 0) { ls[t >> 6] = s; lq[t >> 6] = q; }
    __syncthreads();
    if (t == 0) {
        float ts = (ls[0] + ls[1]) + (ls[2] + ls[3]);
        float tq = (lq[0] + lq[1]) + (lq[2] + lq[3]);
        float mean = ts * (1.0f / BNP);
        float var  = tq * (1.0f / BNP) - mean * mean;
        float a = gamma[c] * rsqrtf(var + BN_EPS);
        scalesh[c]        = a;
        scalesh[COUT + c] = beta[c] - mean * a;
    }
}

// ---------------- K3: apply BN in place on out [B][OUT][N] ------------------
__global__ __launch_bounds__(256) void k_apply(float* __restrict__ out,
                                               const float* __restrict__ scalesh)
{
    __shared__ float sc[COUT], sh[COUT];
    int t = threadIdx.x;
    if (t < COUT) { sc[t] = scalesh[t]; sh[t] = scalesh[COUT + t]; }
    __syncthreads();
    const int total4 = BATCH * COUT * NPTS / 4;
    for (int i = blockIdx.x * 256 + t; i < total4; i += gridDim.x * 256) {
        int ch = (i >> 12) & 127;
        float4 v = ((float4*)out)[i];
        float a = sc[ch], b2 = sh[ch];
        v.x = fmaf(v.x, a, b2); v.y = fmaf(v.y, a, b2);
        v.z = fmaf(v.z, a, b2); v.w = fmaf(v.w, a, b2);
        ((float4*)out)[i] = v;
    }
}

extern "C" void kernel_launch(void* const* d_in, const int* in_sizes, int n_in,
                              void* d_out, int out_size, void* d_ws, size_t ws_size,
                              hipStream_t stream)
{
    const float* feat  = (const float*)d_in[0];
    const int*   nidx  = (const int*)  d_in[1];
    // d_in[2] = permatrix (unused); d_in[5] = b_conv (exactly absorbed by BN)
    const float* Wm    = (const float*)d_in[3];
    const float* Wc    = (const float*)d_in[4];
    const float* gamma = (const float*)d_in[6];
    const float* beta  = (const float*)d_in[7];
    float* out = (float*)d_out;

    unsigned short* fb = (unsigned short*)d_ws;                        // 8.4 MB
    float* part    = (float*)((char*)d_ws + (size_t)BNP * CIN * 2);    // 512 KB
    float* scalesh = part + (size_t)K1_GRID * 256;                     // 256 floats

    k_prep <<<1024,    256, 0, stream>>>(feat, fb);
    k_main <<<K1_GRID, 256, 0, stream>>>(fb, nidx, Wm, Wc, out, part);
    k_stats<<<COUT,    256, 0, stream>>>(part, gamma, beta, scalesh);
    k_apply<<<2048,    256, 0, stream>>>(out, scalesh);
}